// Round 10
// baseline (1272.766 us; speedup 1.0000x reference)
//
#include <hip/hip_runtime.h>

// Problem constants
#define NROWS   16384      // 16*32*32 flattened (b,h,w) rows
#define KCODES  8192
#define CDIM    256
#define HWS     1024       // 32*32
#define BSTRIDE 262144     // 256*1024 floats per batch in z / out

// Workspace layout (float-unit offsets) -- 8 slices
#define WS_AN   0                         // ||x||^2 per row       [16384]
#define WS_CE   16384                     // ||e||^2 per code      [8192]
#define WS_CD   24576                     // cand dist [n*8+slice] [131072]
#define WS_CI   155648                    // cand idx  (int)       [131072]
#define WS_IDX  286720                    // final idx (int)       [16384]
#define WS_LOSS 303104                    // loss accumulator      [1]

// -------- row norms, replicating numpy pairwise_sum order exactly --------
__global__ void rownorm_z_k(const float* __restrict__ z, float* __restrict__ An) {
#pragma clang fp contract(off)
  int n = blockIdx.x * 256 + threadIdx.x;                    // 16384 threads
  const float* base = z + ((size_t)(n >> 10)) * BSTRIDE + (n & 1023);
  float hs[2];
  for (int h = 0; h < 2; ++h) {
    float r[8];
#pragma unroll
    for (int j = 0; j < 8; ++j) { float v = base[(size_t)(h * 128 + j) * HWS]; r[j] = v * v; }
    for (int m = 1; m < 16; ++m) {
#pragma unroll
      for (int j = 0; j < 8; ++j) { float v = base[(size_t)(h * 128 + m * 8 + j) * HWS]; r[j] += v * v; }
    }
    hs[h] = ((r[0] + r[1]) + (r[2] + r[3])) + ((r[4] + r[5]) + (r[6] + r[7]));
  }
  An[n] = hs[0] + hs[1];
}

__global__ void rownorm_e_k(const float* __restrict__ emb, float* __restrict__ Ce) {
#pragma clang fp contract(off)
  int n = blockIdx.x * 256 + threadIdx.x;                    // 8192 threads
  const float* base = emb + (size_t)n * CDIM;
  float hs[2];
  for (int h = 0; h < 2; ++h) {
    float r[8];
#pragma unroll
    for (int j = 0; j < 8; ++j) { float v = base[h * 128 + j]; r[j] = v * v; }
    for (int m = 1; m < 16; ++m) {
#pragma unroll
      for (int j = 0; j < 8; ++j) { float v = base[h * 128 + m * 8 + j]; r[j] += v * v; }
    }
    hs[h] = ((r[0] + r[1]) + (r[2] + r[3])) + ((r[4] + r[5]) + (r[6] + r[7]));
  }
  Ce[n] = hs[0] + hs[1];
}

// -------- fused distance + argmin --------
// 512 blocks = 64 row-tiles (256 rows) x 8 code-slices (1024 codes each)
// = 2 blocks/CU. 256 threads = 16 tx x 16 ty. MICRO-TILE 16 ROWS x 8 CODES.
//
// Round-9 lesson: explicit LDS double-buffering regressed (188 VGPR + 64KB
// LDS -> 12% occupancy; vmcnt wait landed on the critical path). Reverted to
// round-8's single-buffer 2-barrier superstep, which measured best (942us).
// Round-10 change: 16x8 micro-tile doubles FMAs per superstep (4096) while
// reads grow only 1.5x (192 b128) -> LDS cycles, barriers, staging and fold
// VALU per FLOP all halve vs round 8. acc[16][8]=128 regs; live ~220 -> 2
// waves/SIMD (round 9 showed the allocator handles ~190 without spilling;
// WRITE_SIZE is the spill tripwire -- rounds 1-2: squeeze -> GBs of scratch).
// Bank layout (round-8 scheme, 128B rows + 3-bit XOR swizzle on k-groups):
// A reads/B reads few-distinct-addr (broadcast-heavy), B stores 8-phase
// floor, A stores 4-way (was 2-way; 32 stores, minor).
// Accumulation order per (row,code) is IDENTICAL to round 8 (kc->sc->g->
// k3-first fmaf): bit-exact results.
__global__ void __launch_bounds__(256)
vq_argmin_k(const float* __restrict__ z, const float* __restrict__ emb,
            const float* __restrict__ An, const float* __restrict__ Ce,
            float* __restrict__ cand_d, int* __restrict__ cand_i) {
  __shared__ float smem[12288];    // 48 KB: As=[0,8192) [256 rows][32], Bs=[8192,12288) [128 codes][32]
  float* As = smem;
  float* Bs = smem + 8192;

  const int t  = threadIdx.x;
  const int tx = t & 15;           // code group (8 codes, stride 16)
  const int ty = t >> 4;           // row group (16 consecutive rows)
  const int tile  = blockIdx.x >> 3;
  const int slice = blockIdx.x & 7;
  const int rbase = tile * 256;    // 256 | 1024 -> never crosses batch edge
  const int k0    = slice * 1024;

  const float* zb = z + ((size_t)(rbase >> 10)) * BSTRIDE + (rbase & 1023);

  float best[16];
  int   bidx[16];
#pragma unroll
  for (int ri = 0; ri < 16; ++ri) { best[ri] = 3.4028235e38f; bidx[ri] = 0; }

  float acc[16][8];
#pragma unroll
  for (int ri = 0; ri < 16; ++ri)
#pragma unroll
    for (int ci = 0; ci < 8; ++ci) acc[ri][ci] = 0.f;

  // staging thread mappings
  // A: 256 rows x 32 c; thread stages 8 rows x 4 c (c = a_c + 8m)
  const int a_c   = t >> 5;         // 0..7
  const int a_hw  = (t & 31) * 8;   // 8 consecutive rows; (row>>3) = t&31 const
  const int a_swr = (t & 31) & 7;   // (row>>3)&7 for all 8 staged rows
  const int a_wi  = a_c & 3;        // in-group k offset (must stay k-ordered)
  const int a_kg  = a_c >> 2;       // 0 or 1; c+8m -> kg+2m
  // B: 128 codes x 32 c; thread stages 1 code x 16 c (two b128)
  const int b_code = t >> 1;        // code 0..127
  const int b_cb   = (t & 1) * 16;  // c_local base 0 or 16
  const int b_swr  = (t >> 1) & 7;  // code&7
  const int b_kg0  = b_cb >> 2;     // 0 or 4

  const int rd_b_sw  = tx & 7;
  const int rd_a_sw0 = (2 * ty) & 7;      // rows ty*16..+7  ((row>>3)&7)
  const int rd_a_sw1 = (2 * ty + 1) & 7;  // rows ty*16+8..+15
  const int aRowBase0 = (ty * 16) << 5;
  const int aRowBase1 = (ty * 16 + 8) << 5;
  const int bColBase  = tx << 5;

#pragma unroll 1
  for (int s = 0; s < 64; ++s) {     // kc = s>>3, sc = s&7
    const int sc = s & 7;
    const int kc = s >> 3;

    // short prefetch: issue just before barrier; regs die at the stores
    float4 pa[8];
#pragma unroll
    for (int m = 0; m < 4; ++m) {
      const float* zsrc = zb + (size_t)(sc * 32 + a_c + 8 * m) * HWS + a_hw;
      pa[2 * m]     = *(const float4*)(zsrc);
      pa[2 * m + 1] = *(const float4*)(zsrc + 4);
    }
    const float* bsrc = emb + (size_t)(k0 + kc * 128 + b_code) * CDIM + sc * 32 + b_cb;
    const float4 pb0 = *(const float4*)(bsrc);
    const float4 pb1 = *(const float4*)(bsrc + 4);
    const float4 pb2 = *(const float4*)(bsrc + 8);
    const float4 pb3 = *(const float4*)(bsrc + 12);

    __syncthreads();                      // prior compute done with As/Bs
    {
      // A transpose-store: 4 c-columns x 8 rows, col const per column
#pragma unroll
      for (int m = 0; m < 4; ++m) {
        const int col = (((a_kg + 2 * m) ^ a_swr) << 2) | a_wi;
        const float va[8] = {pa[2*m].x, pa[2*m].y, pa[2*m].z, pa[2*m].w,
                             pa[2*m+1].x, pa[2*m+1].y, pa[2*m+1].z, pa[2*m+1].w};
#pragma unroll
        for (int j = 0; j < 8; ++j) As[((a_hw + j) << 5) + col] = va[j];
      }
      // B store: four aligned float4 at swizzled k-group slots
      const int bb = b_code << 5;
      *(float4*)&Bs[bb + (((b_kg0 + 0) ^ b_swr) << 2)] = pb0;
      *(float4*)&Bs[bb + (((b_kg0 + 1) ^ b_swr) << 2)] = pb1;
      *(float4*)&Bs[bb + (((b_kg0 + 2) ^ b_swr) << 2)] = pb2;
      *(float4*)&Bs[bb + (((b_kg0 + 3) ^ b_swr) << 2)] = pb3;
    }
    __syncthreads();                      // staged data visible

    // 16x8 micro-tile over 32 k: 4096 FMA instrs, 192 b128 reads
#pragma unroll
    for (int g = 0; g < 8; ++g) {
      float4 bf[8];
#pragma unroll
      for (int ci = 0; ci < 8; ++ci)
        bf[ci] = *(const float4*)&Bs[bColBase + (ci << 9) + ((g ^ rd_b_sw) << 2)];
      const int aOfs0 = (g ^ rd_a_sw0) << 2;
      const int aOfs1 = (g ^ rd_a_sw1) << 2;
#pragma unroll
      for (int ri = 0; ri < 16; ++ri) {
        const float4 a = (ri < 8)
          ? *(const float4*)&As[aRowBase0 + (ri << 5) + aOfs0]
          : *(const float4*)&As[aRowBase1 + ((ri - 8) << 5) + aOfs1];
#pragma unroll
        for (int ci = 0; ci < 8; ++ci) {
          // 4-k groups ascending, k3-first nesting: identical to rounds 1-9
          acc[ri][ci] = fmaf(a.x, bf[ci].x, fmaf(a.y, bf[ci].y,
                        fmaf(a.z, bf[ci].z, fmaf(a.w, bf[ci].w, acc[ri][ci]))));
        }
      }
    }

    if (sc == 7) {
      // fold per kc: dist = (A - 2*dot) + C, np's elementwise fp32 rounding.
      // thread's codes ascend with ci (tx + ci*16) + strict < -> lowest-index
      // min within thread; cross-thread/slice merges compare indices.
      const int kkb = k0 + kc * 128 + tx;
      float cearr[8];
#pragma unroll
      for (int ci = 0; ci < 8; ++ci) cearr[ci] = Ce[kkb + ci * 16];
#pragma unroll
      for (int ri = 0; ri < 16; ++ri) {
        const float Ar = An[rbase + ty * 16 + ri];   // reload (saves live regs)
#pragma unroll
        for (int ci = 0; ci < 8; ++ci) {
          const float d = (Ar - 2.0f * acc[ri][ci]) + cearr[ci];
          if (d < best[ri]) { best[ri] = d; bidx[ri] = kkb + ci * 16; }
          acc[ri][ci] = 0.f;
        }
      }
    }
  }

  // cross-thread argmin per row (tie -> lower absolute index); alias smem
  __syncthreads();                 // compute done; safe to overwrite As/Bs
  float* redd = smem;              // [256][16]
  int*   redi = (int*)(smem + 4096);
#pragma unroll
  for (int ri = 0; ri < 16; ++ri) {
    redd[(ty * 16 + ri) * 16 + tx] = best[ri];
    redi[(ty * 16 + ri) * 16 + tx] = bidx[ri];
  }
  __syncthreads();
  {
    float bd = redd[t * 16];
    int   bi = redi[t * 16];
    for (int j = 1; j < 16; ++j) {
      const float d  = redd[t * 16 + j];
      const int   i2 = redi[t * 16 + j];
      if (d < bd || (d == bd && i2 < bi)) { bd = d; bi = i2; }
    }
    const int n = rbase + t;
    cand_d[n * 8 + slice] = bd;
    cand_i[n * 8 + slice] = bi;
  }
}

// -------- merge the 8 code-slices (tie -> lower index) --------
__global__ void vq_merge_k(const float* __restrict__ cand_d, const int* __restrict__ cand_i,
                           int* __restrict__ idx_final, float* __restrict__ idxf_out) {
  const int n = blockIdx.x * 256 + threadIdx.x;   // 16384
  float bd = cand_d[n * 8];
  int   bi = cand_i[n * 8];
#pragma unroll
  for (int s = 1; s < 8; ++s) {
    const float d  = cand_d[n * 8 + s];
    const int   i2 = cand_i[n * 8 + s];
    if (d < bd || (d == bd && i2 < bi)) { bd = d; bi = i2; }
  }
  idx_final[n] = bi;
  idxf_out[n] = (float)bi;
}

// -------- gather quantized, write straight-through output, accumulate loss ----
// quantized_st = z + (q - z) in fp32 (matches np rounding; != q exactly).
__launch_bounds__(256)
__global__ void vq_gather_loss_k(const float* __restrict__ z, const float* __restrict__ emb,
                                 const int* __restrict__ idx_final,
                                 float* __restrict__ qout, float* __restrict__ loss_acc) {
  __shared__ float Qs[32 * 260];
  __shared__ int   kidx[32];
  __shared__ float warp_s[4];
  const int t = threadIdx.x;
  const int rbase = blockIdx.x * 32;
  if (t < 32) kidx[t] = idx_final[rbase + t];
  __syncthreads();
  {
    const int r = t >> 3, cp = t & 7;
    const float4* er = (const float4*)(emb + (size_t)kidx[r] * CDIM);
#pragma unroll
    for (int j = 0; j < 8; ++j) {
      const int c4 = cp + j * 8;
      const float4 v = er[c4];
      *(float4*)&Qs[r * 260 + c4 * 4] = v;
    }
  }
  __syncthreads();
  const int b = rbase >> 10, hw0 = rbase & 1023;
  const float* zb = z + (size_t)b * BSTRIDE + hw0;
  float* qb = qout + (size_t)b * BSTRIDE + hw0;
  float s = 0.f;
  const int hwl = t & 31, cg = t >> 5;
  for (int i = 0; i < 32; ++i) {
    const int c = cg * 32 + i;
    const float q  = Qs[hwl * 260 + c];
    const size_t off = (size_t)c * HWS + hwl;
    const float zv = zb[off];
    const float d  = q - zv;
    qb[off] = zv + d;          // straight-through value, np rounding
    s += d * d;
  }
  for (int off = 32; off; off >>= 1) s += __shfl_down(s, off, 64);
  if ((t & 63) == 0) warp_s[t >> 6] = s;
  __syncthreads();
  if (t == 0) atomicAdd(loss_acc, warp_s[0] + warp_s[1] + warp_s[2] + warp_s[3]);
}

__global__ void vq_finalize_k(const float* __restrict__ loss_acc, float* __restrict__ out_loss) {
  const float m = loss_acc[0] * (1.0f / 4194304.0f);
  out_loss[0] = m;          // codebook_loss
  out_loss[1] = 0.25f * m;  // commitment_loss (BETA * same mean)
}

extern "C" void kernel_launch(void* const* d_in, const int* in_sizes, int n_in,
                              void* d_out, int out_size, void* d_ws, size_t ws_size,
                              hipStream_t stream) {
  (void)in_sizes; (void)n_in; (void)out_size; (void)ws_size;
  const float* z   = (const float*)d_in[0];
  const float* emb = (const float*)d_in[1];
  float* out      = (float*)d_out;
  float* q_out    = out;                 // [16,256,32,32]
  float* loss_out = out + 4194304;       // 2 scalars
  float* idxf_out = out + 4194306;       // [16,32,32] as float

  float* ws       = (float*)d_ws;
  float* An       = ws + WS_AN;
  float* Ce       = ws + WS_CE;
  float* cand_d   = ws + WS_CD;
  int*   cand_i   = (int*)(ws + WS_CI);
  int*   idx_fin  = (int*)(ws + WS_IDX);
  float* loss_acc = ws + WS_LOSS;

  hipMemsetAsync(loss_acc, 0, sizeof(float), stream);
  rownorm_z_k<<<64, 256, 0, stream>>>(z, An);
  rownorm_e_k<<<32, 256, 0, stream>>>(emb, Ce);
  vq_argmin_k<<<512, 256, 0, stream>>>(z, emb, An, Ce, cand_d, cand_i);
  vq_merge_k<<<64, 256, 0, stream>>>(cand_d, cand_i, idx_fin, idxf_out);
  vq_gather_loss_k<<<512, 256, 0, stream>>>(z, emb, idx_fin, q_out, loss_acc);
  vq_finalize_k<<<1, 1, 0, stream>>>(loss_acc, loss_out);
}

// Round 13
// 941.176 us; speedup vs baseline: 1.3523x; 1.3523x over previous
//
#include <hip/hip_runtime.h>

// Problem constants
#define NROWS   16384      // 16*32*32 flattened (b,h,w) rows
#define KCODES  8192
#define CDIM    256
#define HWS     1024       // 32*32
#define BSTRIDE 262144     // 256*1024 floats per batch in z / out

// Workspace layout (float-unit offsets) -- 8 slices
#define WS_AN   0                         // ||x||^2 per row       [16384]
#define WS_CE   16384                     // ||e||^2 per code      [8192]
#define WS_CD   24576                     // cand dist [n*8+slice] [131072]
#define WS_CI   155648                    // cand idx  (int)       [131072]
#define WS_IDX  286720                    // final idx (int)       [16384]
#define WS_LOSS 303104                    // loss accumulator      [1]

// -------- row norms, replicating numpy pairwise_sum order exactly --------
__global__ void rownorm_z_k(const float* __restrict__ z, float* __restrict__ An) {
#pragma clang fp contract(off)
  int n = blockIdx.x * 256 + threadIdx.x;                    // 16384 threads
  const float* base = z + ((size_t)(n >> 10)) * BSTRIDE + (n & 1023);
  float hs[2];
  for (int h = 0; h < 2; ++h) {
    float r[8];
#pragma unroll
    for (int j = 0; j < 8; ++j) { float v = base[(size_t)(h * 128 + j) * HWS]; r[j] = v * v; }
    for (int m = 1; m < 16; ++m) {
#pragma unroll
      for (int j = 0; j < 8; ++j) { float v = base[(size_t)(h * 128 + m * 8 + j) * HWS]; r[j] += v * v; }
    }
    hs[h] = ((r[0] + r[1]) + (r[2] + r[3])) + ((r[4] + r[5]) + (r[6] + r[7]));
  }
  An[n] = hs[0] + hs[1];
}

__global__ void rownorm_e_k(const float* __restrict__ emb, float* __restrict__ Ce) {
#pragma clang fp contract(off)
  int n = blockIdx.x * 256 + threadIdx.x;                    // 8192 threads
  const float* base = emb + (size_t)n * CDIM;
  float hs[2];
  for (int h = 0; h < 2; ++h) {
    float r[8];
#pragma unroll
    for (int j = 0; j < 8; ++j) { float v = base[h * 128 + j]; r[j] = v * v; }
    for (int m = 1; m < 16; ++m) {
#pragma unroll
      for (int j = 0; j < 8; ++j) { float v = base[h * 128 + m * 8 + j]; r[j] += v * v; }
    }
    hs[h] = ((r[0] + r[1]) + (r[2] + r[3])) + ((r[4] + r[5]) + (r[6] + r[7]));
  }
  Ce[n] = hs[0] + hs[1];
}

// -------- fused distance + argmin --------
// EXACT Round-8 kernel: the only configuration that passed the complete
// harness (graph-capture timing + post-timing revalidation) at 939us total.
// Session landscape around it (all verified regressions or failures):
//   4x4 tile: LDS-issue bound ~1040us | 16x8 tile: 188-VGPR cliff 1341us
//   LDS dbuf: same cliff + exposed vmcnt 1287us | skewed-row addressing:
//   replay-correctness hazard (R11/R12). 8x8 + 32-c superchunk + 4 blocks/CU
//   + XOR-swizzled banks is the measured structural optimum.
// 1024 blocks = 128 row-tiles (128 rows) x 8 code-slices (1024 codes each).
// 256 threads = 16 tx x 16 ty. Micro-tile 8 rows x 8 codes.
//
// LDS: 128B rows (32 floats) + 3-bit XOR swizzle col=((kg^swz)<<2)|wi:
//   A reads:  quad = g ^ (ty&7), 4 distinct/wave -> 1 phase (conflict-free)
//   B reads:  quad = g ^ (tx&7), 8 quads x 2     -> 2 phases (free, m136)
//   A stores: bank = 4*((t&15)&7) + (t>>4), all 32 banks 2-way (free)
//   B stores: 64 distinct b128 addrs, 8/quad     -> 8-phase floor
// Registers: acc 64 + bf 32 + staging + addr ~= 120 VGPR -> 4 waves/SIMD.
// WRITE_SIZE ~8e3 KB is the no-spill tripwire (rounds 1-2: allocator
// squeeze -> GBs of scratch traffic).
__global__ void __launch_bounds__(256)
vq_argmin_k(const float* __restrict__ z, const float* __restrict__ emb,
            const float* __restrict__ An, const float* __restrict__ Ce,
            float* __restrict__ cand_d, int* __restrict__ cand_i) {
  __shared__ float smem[8192];     // 32 KB: As=[0,4096), Bs=[4096,8192)
  float* As = smem;                // [row][32 c], col XOR-swizzled by (row>>3)&7
  float* Bs = smem + 4096;         // [code][32 c], col XOR-swizzled by code&7

  const int t  = threadIdx.x;
  const int tx = t & 15;           // code group (8 codes, stride 16)
  const int ty = t >> 4;           // row group (8 consecutive rows)
  const int tile  = blockIdx.x >> 3;
  const int slice = blockIdx.x & 7;
  const int rbase = tile * 128;    // never crosses the 1024-hw batch edge
  const int k0    = slice * 1024;

  const float* zb = z + ((size_t)(rbase >> 10)) * BSTRIDE + (rbase & 1023);

  float best[8];
  int   bidx[8];
#pragma unroll
  for (int ri = 0; ri < 8; ++ri) { best[ri] = 3.4028235e38f; bidx[ri] = 0; }

  float acc[8][8];
#pragma unroll
  for (int ri = 0; ri < 8; ++ri)
#pragma unroll
    for (int ci = 0; ci < 8; ++ci) acc[ri][ci] = 0.f;

  // staging thread mappings
  const int a_c   = t >> 4;         // stages c_locals {a_c, a_c+16}, 8 rows each
  const int a_hw  = (t & 15) * 8;   // 8 consecutive rows
  const int a_swr = (t & 15) & 7;   // (row>>3)&7 for all 8 staged rows
  const int a_wi  = a_c & 3;
  const int a_kg1 = a_c >> 2;
  const int acol1 = ((a_kg1 ^ a_swr) << 2) | a_wi;
  const int acol2 = (((a_kg1 + 4) ^ a_swr) << 2) | a_wi;
  const int b_code  = t >> 1;       // code 0..127
  const int b_cb    = (t & 1) * 16; // c_local base 0 or 16
  const int b_swr   = (t >> 1) & 7; // code&7
  const int b_kg0   = b_cb >> 2;    // 0 or 4

  const int rd_a_sw = ty & 7;
  const int rd_b_sw = tx & 7;

  for (int kc = 0; kc < 8; ++kc) {
    const int kbase = k0 + kc * 128;
#pragma unroll 1
    for (int sc = 0; sc < 8; ++sc) {
      // short prefetch: issue just before barrier; regs die at the stores
      const float* zsrc = zb + (size_t)(sc * 32 + a_c) * HWS + a_hw;
      const float4 pa0 = *(const float4*)(zsrc);
      const float4 pa1 = *(const float4*)(zsrc + 4);
      const float4 pa2 = *(const float4*)(zsrc + 16 * HWS);
      const float4 pa3 = *(const float4*)(zsrc + 16 * HWS + 4);
      const float* bsrc = emb + (size_t)(kbase + b_code) * CDIM + sc * 32 + b_cb;
      const float4 pb0 = *(const float4*)(bsrc);
      const float4 pb1 = *(const float4*)(bsrc + 4);
      const float4 pb2 = *(const float4*)(bsrc + 8);
      const float4 pb3 = *(const float4*)(bsrc + 12);

      __syncthreads();                      // prior compute done with As/Bs
      {
        // A transpose-store: 16 scalar stores, col const per thread (2-way free)
        const float va0[8] = {pa0.x, pa0.y, pa0.z, pa0.w, pa1.x, pa1.y, pa1.z, pa1.w};
        const float va1[8] = {pa2.x, pa2.y, pa2.z, pa2.w, pa3.x, pa3.y, pa3.z, pa3.w};
#pragma unroll
        for (int j = 0; j < 8; ++j) {
          const int rb = (a_hw + j) << 5;
          As[rb + acol1] = va0[j];
          As[rb + acol2] = va1[j];
        }
        // B store: four aligned float4 at swizzled k-group slots (8-phase floor)
        const int bb = b_code << 5;
        *(float4*)&Bs[bb + (((b_kg0 + 0) ^ b_swr) << 2)] = pb0;
        *(float4*)&Bs[bb + (((b_kg0 + 1) ^ b_swr) << 2)] = pb1;
        *(float4*)&Bs[bb + (((b_kg0 + 2) ^ b_swr) << 2)] = pb2;
        *(float4*)&Bs[bb + (((b_kg0 + 3) ^ b_swr) << 2)] = pb3;
      }
      __syncthreads();                      // staged data visible

      // 8x8 micro-tile over 32 k: 2048 FMA instrs, 128 b128 reads
#pragma unroll
      for (int g = 0; g < 8; ++g) {
        float4 bf[8];
#pragma unroll
        for (int ci = 0; ci < 8; ++ci)
          bf[ci] = *(const float4*)&Bs[((tx + ci * 16) << 5) + ((g ^ rd_b_sw) << 2)];
#pragma unroll
        for (int ri = 0; ri < 8; ++ri) {
          const float4 a = *(const float4*)&As[((ty * 8 + ri) << 5) + ((g ^ rd_a_sw) << 2)];
#pragma unroll
          for (int ci = 0; ci < 8; ++ci) {
            // 4-k groups ascending, k3-first nesting: identical to rounds 1-8
            acc[ri][ci] = fmaf(a.x, bf[ci].x, fmaf(a.y, bf[ci].y,
                          fmaf(a.z, bf[ci].z, fmaf(a.w, bf[ci].w, acc[ri][ci]))));
          }
        }
      }
    }

    // fold per kc: dist = (A - 2*dot) + C with np's elementwise fp32 rounding.
    // thread's codes ascend with ci (tx + ci*16) + strict < -> lowest-index
    // min within thread; cross-thread/slice merges compare indices explicitly.
    {
      const int kkb = kbase + tx;
      float cearr[8];
#pragma unroll
      for (int ci = 0; ci < 8; ++ci) cearr[ci] = Ce[kkb + ci * 16];
#pragma unroll
      for (int ri = 0; ri < 8; ++ri) {
        const float Ar = An[rbase + ty * 8 + ri];   // reload (saves live regs)
#pragma unroll
        for (int ci = 0; ci < 8; ++ci) {
          const float d = (Ar - 2.0f * acc[ri][ci]) + cearr[ci];
          if (d < best[ri]) { best[ri] = d; bidx[ri] = kkb + ci * 16; }
          acc[ri][ci] = 0.f;
        }
      }
    }
  }

  // cross-thread argmin per row (tie -> lower absolute index); alias smem
  __syncthreads();                 // compute done; safe to overwrite As/Bs
  float* redd = smem;              // [128][16]
  int*   redi = (int*)(smem + 2048);
#pragma unroll
  for (int ri = 0; ri < 8; ++ri) {
    redd[(ty * 8 + ri) * 16 + tx] = best[ri];
    redi[(ty * 8 + ri) * 16 + tx] = bidx[ri];
  }
  __syncthreads();
  if (t < 128) {
    float bd = redd[t * 16];
    int   bi = redi[t * 16];
    for (int j = 1; j < 16; ++j) {
      const float d  = redd[t * 16 + j];
      const int   i2 = redi[t * 16 + j];
      if (d < bd || (d == bd && i2 < bi)) { bd = d; bi = i2; }
    }
    const int n = rbase + t;
    cand_d[n * 8 + slice] = bd;
    cand_i[n * 8 + slice] = bi;
  }
}

// -------- merge the 8 code-slices (tie -> lower index) --------
__global__ void vq_merge_k(const float* __restrict__ cand_d, const int* __restrict__ cand_i,
                           int* __restrict__ idx_final, float* __restrict__ idxf_out) {
  const int n = blockIdx.x * 256 + threadIdx.x;   // 16384
  float bd = cand_d[n * 8];
  int   bi = cand_i[n * 8];
#pragma unroll
  for (int s = 1; s < 8; ++s) {
    const float d  = cand_d[n * 8 + s];
    const int   i2 = cand_i[n * 8 + s];
    if (d < bd || (d == bd && i2 < bi)) { bd = d; bi = i2; }
  }
  idx_final[n] = bi;
  idxf_out[n] = (float)bi;
}

// -------- gather quantized, write straight-through output, accumulate loss ----
// quantized_st = z + (q - z) in fp32 (matches np rounding; != q exactly).
__launch_bounds__(256)
__global__ void vq_gather_loss_k(const float* __restrict__ z, const float* __restrict__ emb,
                                 const int* __restrict__ idx_final,
                                 float* __restrict__ qout, float* __restrict__ loss_acc) {
  __shared__ float Qs[32 * 260];
  __shared__ int   kidx[32];
  __shared__ float warp_s[4];
  const int t = threadIdx.x;
  const int rbase = blockIdx.x * 32;
  if (t < 32) kidx[t] = idx_final[rbase + t];
  __syncthreads();
  {
    const int r = t >> 3, cp = t & 7;
    const float4* er = (const float4*)(emb + (size_t)kidx[r] * CDIM);
#pragma unroll
    for (int j = 0; j < 8; ++j) {
      const int c4 = cp + j * 8;
      const float4 v = er[c4];
      *(float4*)&Qs[r * 260 + c4 * 4] = v;
    }
  }
  __syncthreads();
  const int b = rbase >> 10, hw0 = rbase & 1023;
  const float* zb = z + (size_t)b * BSTRIDE + hw0;
  float* qb = qout + (size_t)b * BSTRIDE + hw0;
  float s = 0.f;
  const int hwl = t & 31, cg = t >> 5;
  for (int i = 0; i < 32; ++i) {
    const int c = cg * 32 + i;
    const float q  = Qs[hwl * 260 + c];
    const size_t off = (size_t)c * HWS + hwl;
    const float zv = zb[off];
    const float d  = q - zv;
    qb[off] = zv + d;          // straight-through value, np rounding
    s += d * d;
  }
  for (int off = 32; off; off >>= 1) s += __shfl_down(s, off, 64);
  if ((t & 63) == 0) warp_s[t >> 6] = s;
  __syncthreads();
  if (t == 0) atomicAdd(loss_acc, warp_s[0] + warp_s[1] + warp_s[2] + warp_s[3]);
}

__global__ void vq_finalize_k(const float* __restrict__ loss_acc, float* __restrict__ out_loss) {
  const float m = loss_acc[0] * (1.0f / 4194304.0f);
  out_loss[0] = m;          // codebook_loss
  out_loss[1] = 0.25f * m;  // commitment_loss (BETA * same mean)
}

extern "C" void kernel_launch(void* const* d_in, const int* in_sizes, int n_in,
                              void* d_out, int out_size, void* d_ws, size_t ws_size,
                              hipStream_t stream) {
  (void)in_sizes; (void)n_in; (void)out_size; (void)ws_size;
  const float* z   = (const float*)d_in[0];
  const float* emb = (const float*)d_in[1];
  float* out      = (float*)d_out;
  float* q_out    = out;                 // [16,256,32,32]
  float* loss_out = out + 4194304;       // 2 scalars
  float* idxf_out = out + 4194306;       // [16,32,32] as float

  float* ws       = (float*)d_ws;
  float* An       = ws + WS_AN;
  float* Ce       = ws + WS_CE;
  float* cand_d   = ws + WS_CD;
  int*   cand_i   = (int*)(ws + WS_CI);
  int*   idx_fin  = (int*)(ws + WS_IDX);
  float* loss_acc = ws + WS_LOSS;

  hipMemsetAsync(loss_acc, 0, sizeof(float), stream);
  rownorm_z_k<<<64, 256, 0, stream>>>(z, An);
  rownorm_e_k<<<32, 256, 0, stream>>>(emb, Ce);
  vq_argmin_k<<<1024, 256, 0, stream>>>(z, emb, An, Ce, cand_d, cand_i);
  vq_merge_k<<<64, 256, 0, stream>>>(cand_d, cand_i, idx_fin, idxf_out);
  vq_gather_loss_k<<<512, 256, 0, stream>>>(z, emb, idx_fin, q_out, loss_acc);
  vq_finalize_k<<<1, 1, 0, stream>>>(loss_acc, loss_out);
}